// Round 1
// baseline (1152.695 us; speedup 1.0000x reference)
//
#include <hip/hip_runtime.h>

typedef unsigned short u16;
typedef __bf16 bf16x8 __attribute__((ext_vector_type(8)));
typedef float f32x4 __attribute__((ext_vector_type(4)));

#define B_   256
#define C_   2048
#define P_   196
#define A_   512
#define CP_  (C_ * P_)        // 401408
#define MTOT (B_ * P_)        // 50176 = 784 * 64

__device__ __forceinline__ u16 f2bf(float f) {
    unsigned int x = __float_as_uint(f);
    unsigned int r = (x + 0x7fffu + ((x >> 16) & 1u)) >> 16;   // RNE
    return (u16)r;
}

// ---------------------------------------------------------------------------
// Kernel 1: Wt[a][c] = bf16(W_enc[c][a])   (2048x512 -> 512x2048)
// ---------------------------------------------------------------------------
__global__ __launch_bounds__(256) void k_transpose_wenc(const float* __restrict__ W,
                                                        u16* __restrict__ Wt) {
    __shared__ u16 tile[64][65];
    int t  = threadIdx.x;
    int cb = (blockIdx.x & 31) * 64;   // 32 c-blocks
    int ab = (blockIdx.x >> 5) * 64;   // 8  a-blocks
#pragma unroll
    for (int i = 0; i < 16; ++i) {
        int c = (t >> 6) + i * 4;
        int a = t & 63;
        tile[c][a] = f2bf(W[(size_t)(cb + c) * A_ + ab + a]);
    }
    __syncthreads();
#pragma unroll
    for (int i = 0; i < 16; ++i) {
        int a  = (t >> 6) + i * 4;
        int cl = t & 63;
        Wt[(size_t)(ab + a) * C_ + cb + cl] = tile[cl][a];
    }
}

// ---------------------------------------------------------------------------
// Kernel 2: dec_att[b][a] = dh[b] @ W_dec[:,a] + b_dec[a]
// ---------------------------------------------------------------------------
__global__ __launch_bounds__(512) void k_dec_att(const float* __restrict__ dh,
                                                 const float* __restrict__ Wd,
                                                 const float* __restrict__ bd,
                                                 float* __restrict__ out) {
    __shared__ float hL[512];
    int b = blockIdx.x, t = threadIdx.x;
    hL[t] = dh[b * 512 + t];
    __syncthreads();
    float s = bd[t];
#pragma unroll 8
    for (int k = 0; k < 512; ++k) s = fmaf(hL[k], Wd[k * 512 + t], s);
    out[b * 512 + t] = s;
}

// ---------------------------------------------------------------------------
// Kernel 3: fused  att[r] = sum_a relu(feats[r]@W_enc[:,a] + b_enc[a] +
//                                      dec_att[b(r)][a]) * w_full[a] + b_full
// Computes enc_att^T tile [512 a x 64 r] per block via mfma 16x16x32 bf16.
//   A-operand = Wt rows   (m = a),  B-operand = feats rows (n = r).
// ---------------------------------------------------------------------------
__global__ __launch_bounds__(512, 2) void k_gemm_att(const float* __restrict__ enc,
                                                     const u16* __restrict__ Wt,
                                                     const float* __restrict__ dec_att,
                                                     const float* __restrict__ benc,
                                                     const float* __restrict__ wfull,
                                                     const float* __restrict__ bfull,
                                                     float* __restrict__ att) {
    __shared__ u16   As[64 * 40];     // feats tile  [r][k], row stride 40
    __shared__ u16   Bs[512 * 40];    // Wt   tile   [a][k], row stride 40
    __shared__ float decL[2][512];
    __shared__ float wL[512];
    __shared__ float att_part[512];   // [wave][64 rows]

    const int t    = threadIdx.x;
    const int mb   = blockIdx.x;
    const int row0 = mb * 64;

    // ---- stage per-block constants -------------------------------------
    const int b0 = row0 / 196;
    const int b1 = (row0 + 63) / 196;
    decL[0][t] = dec_att[b0 * 512 + t] + benc[t];
    decL[1][t] = dec_att[b1 * 512 + t] + benc[t];
    wL[t]      = wfull[t];
    att_part[t] = 0.0f;

    // ---- staging roles --------------------------------------------------
    const int r_l = t & 63;          // feats row this thread stages
    const int cg  = t >> 6;          // 0..7 : k-subgroup of 4
    const int rg  = row0 + r_l;
    const int bb  = rg / 196;
    const int pp  = rg - bb * 196;
    const float* srcA = enc + (size_t)bb * CP_ + pp;

    // ---- wave/fragment coordinates -------------------------------------
    const int lane = t & 63;
    const int wv   = t >> 6;         // 0..7
    const int wr   = wv & 1;         // row half (32 rows)
    const int wa   = wv >> 1;        // 0..3 : a-range of 128
    const int col  = lane & 15;
    const int quad = lane >> 4;

    f32x4 acc[8][2] = {};            // [a-tile][r-tile]

    for (int k0 = 0; k0 < C_; k0 += 32) {
        __syncthreads();
        // stage feats: 4 scalar fp32 loads -> bf16 -> one 8B LDS write
        {
            float f0 = srcA[(k0 + cg * 4 + 0) * P_];
            float f1 = srcA[(k0 + cg * 4 + 1) * P_];
            float f2 = srcA[(k0 + cg * 4 + 2) * P_];
            float f3 = srcA[(k0 + cg * 4 + 3) * P_];
            unsigned int lo = (unsigned int)f2bf(f0) | ((unsigned int)f2bf(f1) << 16);
            unsigned int hi = (unsigned int)f2bf(f2) | ((unsigned int)f2bf(f3) << 16);
            unsigned long long v = (unsigned long long)lo | ((unsigned long long)hi << 32);
            *(unsigned long long*)&As[r_l * 40 + cg * 4] = v;
        }
        // stage Wt: thread t = row a, 64B contiguous -> 4x b128
        {
            const uint4* src = (const uint4*)(Wt + (size_t)t * C_ + k0);
            uint4* dst = (uint4*)&Bs[t * 40];
            dst[0] = src[0];
            dst[1] = src[1];
            dst[2] = src[2];
            dst[3] = src[3];
        }
        __syncthreads();

        bf16x8 af[8], bf[2];
#pragma unroll
        for (int tr = 0; tr < 2; ++tr)
            bf[tr] = *(const bf16x8*)&As[(wr * 32 + tr * 16 + col) * 40 + quad * 8];
#pragma unroll
        for (int ta = 0; ta < 8; ++ta)
            af[ta] = *(const bf16x8*)&Bs[(wa * 128 + ta * 16 + col) * 40 + quad * 8];
#pragma unroll
        for (int ta = 0; ta < 8; ++ta)
#pragma unroll
            for (int tr = 0; tr < 2; ++tr)
                acc[ta][tr] = __builtin_amdgcn_mfma_f32_16x16x32_bf16(af[ta], bf[tr],
                                                                      acc[ta][tr], 0, 0, 0);
    }

    // ---- epilogue: relu + dot(w_full) fused, reduce over a -------------
#pragma unroll
    for (int tr = 0; tr < 2; ++tr) {
        int rgl  = wr * 32 + tr * 16 + col;       // local row (n index)
        int rgg  = row0 + rgl;
        int bi   = rgg / 196 - b0;                // 0 or 1
        float s = 0.0f;
#pragma unroll
        for (int ta = 0; ta < 8; ++ta)
#pragma unroll
            for (int rr = 0; rr < 4; ++rr) {
                int a_idx = wa * 128 + ta * 16 + quad * 4 + rr;
                float v = acc[ta][tr][rr] + decL[bi][a_idx];
                s = fmaf(fmaxf(v, 0.0f), wL[a_idx], s);
            }
        s += __shfl_xor(s, 16);
        s += __shfl_xor(s, 32);
        if (quad == 0) att_part[wv * 64 + rgl] = s;
    }
    __syncthreads();
    if (t < 64) {
        float s = bfull[0];
#pragma unroll
        for (int w = 0; w < 8; ++w) s += att_part[w * 64 + t];
        att[row0 + t] = s;
    }
}

// ---------------------------------------------------------------------------
// Kernel 4: softmax over 196 pixels per batch (1 wave per batch)
// ---------------------------------------------------------------------------
__global__ __launch_bounds__(64) void k_softmax(const float* __restrict__ att,
                                                float* __restrict__ alpha) {
    int b = blockIdx.x, lane = threadIdx.x;
    const float* a = att + b * P_;
    float v[4];
    float mx = -__builtin_inff();
#pragma unroll
    for (int i = 0; i < 4; ++i) {
        int p = lane + i * 64;
        v[i] = (p < P_) ? a[p] : -__builtin_inff();
        mx = fmaxf(mx, v[i]);
    }
#pragma unroll
    for (int off = 32; off >= 1; off >>= 1) mx = fmaxf(mx, __shfl_xor(mx, off));
    float sum = 0.0f;
#pragma unroll
    for (int i = 0; i < 4; ++i) {
        int p = lane + i * 64;
        float e = (p < P_) ? expf(v[i] - mx) : 0.0f;
        v[i] = e;
        sum += e;
    }
#pragma unroll
    for (int off = 32; off >= 1; off >>= 1) sum += __shfl_xor(sum, off);
    float inv = 1.0f / sum;
#pragma unroll
    for (int i = 0; i < 4; ++i) {
        int p = lane + i * 64;
        if (p < P_) alpha[b * P_ + p] = v[i] * inv;
    }
}

// ---------------------------------------------------------------------------
// Kernel 5: context[b][c] = sum_p enc[b][c][p] * alpha[b][p]   (fp32 exact)
// block = (b, chunk of 64 c); wave handles 16 c rows; float4 over p (196=49*4)
// ---------------------------------------------------------------------------
__global__ __launch_bounds__(256) void k_context(const float* __restrict__ enc,
                                                 const float* __restrict__ alpha,
                                                 float* __restrict__ ctx) {
    __shared__ float aL[256];
    int t = threadIdx.x;
    int b = blockIdx.x >> 5;
    int chunk = blockIdx.x & 31;
    aL[t] = (t < P_) ? alpha[b * P_ + t] : 0.0f;
    __syncthreads();
    int wv = t >> 6, lane = t & 63;
    int cbase = chunk * 64 + wv * 16;
    const float* base = enc + (size_t)b * CP_;
#pragma unroll 4
    for (int i = 0; i < 16; ++i) {
        int c = cbase + i;
        float s = 0.0f;
        if (lane < 49) {
            float4 f = *(const float4*)(base + (size_t)c * P_ + lane * 4);
            float4 a4 = *(const float4*)&aL[lane * 4];
            s = f.x * a4.x + f.y * a4.y + f.z * a4.z + f.w * a4.w;
        }
#pragma unroll
        for (int off = 32; off >= 1; off >>= 1) s += __shfl_xor(s, off);
        if (lane == 0) ctx[(size_t)b * C_ + c] = s;
    }
}

// ---------------------------------------------------------------------------
extern "C" void kernel_launch(void* const* d_in, const int* in_sizes, int n_in,
                              void* d_out, int out_size, void* d_ws, size_t ws_size,
                              hipStream_t stream) {
    const float* enc   = (const float*)d_in[0];
    const float* dh    = (const float*)d_in[1];
    const float* Wenc  = (const float*)d_in[2];
    const float* benc  = (const float*)d_in[3];
    const float* Wdec  = (const float*)d_in[4];
    const float* bdec  = (const float*)d_in[5];
    const float* wfull = (const float*)d_in[6];
    const float* bfull = (const float*)d_in[7];

    u16*   Wt  = (u16*)d_ws;                                    // 2 MB
    float* dec = (float*)((char*)d_ws + (2u << 20));            // 512 KB
    float* att = (float*)((char*)d_ws + (2u << 20) + (512u << 10)); // 200 KB

    float* ctx     = (float*)d_out;          // [256][2048]
    float* alpha_o = ctx + B_ * C_;          // [256][196]

    k_transpose_wenc<<<dim3(256), dim3(256), 0, stream>>>(Wenc, Wt);
    k_dec_att<<<dim3(256), dim3(512), 0, stream>>>(dh, Wdec, bdec, dec);
    k_gemm_att<<<dim3(MTOT / 64), dim3(512), 0, stream>>>(enc, Wt, dec, benc,
                                                          wfull, bfull, att);
    k_softmax<<<dim3(256), dim3(64), 0, stream>>>(att, alpha_o);
    k_context<<<dim3(256 * 32), dim3(256), 0, stream>>>(enc, alpha_o, ctx);
}

// Round 2
// 1009.004 us; speedup vs baseline: 1.1424x; 1.1424x over previous
//
#include <hip/hip_runtime.h>

typedef unsigned short u16;
typedef __bf16 bf16x8 __attribute__((ext_vector_type(8)));
typedef __bf16 bf16x4 __attribute__((ext_vector_type(4)));
typedef float f32x4 __attribute__((ext_vector_type(4)));

#define B_   256
#define C_   2048
#define P_   196
#define A_   512
#define CP_  (C_ * P_)        // 401408
#define MTOT (B_ * P_)        // 50176 = 784 * 64

__device__ __forceinline__ u16 f2bf(float f) {
    unsigned int x = __float_as_uint(f);
    unsigned int r = (x + 0x7fffu + ((x >> 16) & 1u)) >> 16;   // RNE
    return (u16)r;
}

// async global->LDS 16B copy; LDS dest must be wave-uniform base + lane*16
__device__ __forceinline__ void gl_lds16(const void* g, void* l) {
    __builtin_amdgcn_global_load_lds(
        (const __attribute__((address_space(1))) unsigned int*)g,
        (__attribute__((address_space(3))) unsigned int*)l, 16, 0, 0);
}

// ---------------------------------------------------------------------------
// Kernel 0: fT[(b*196+p)][c] = bf16(enc[b][c][p])   (transpose+convert, 206MB)
// grid: b(256) x cb(32) x pb(4), 256 threads, tile 64c x 64p
// ---------------------------------------------------------------------------
__global__ __launch_bounds__(256) void k_prep_feats(const float* __restrict__ enc,
                                                    u16* __restrict__ fT) {
    __shared__ u16 tile[64][66];     // [p][c], stride 33 words -> conflict-free-ish
    int blk = blockIdx.x;
    int pb = blk & 3, cb = (blk >> 2) & 31, b = blk >> 7;
    int p0 = pb * 64, c0 = cb * 64;
    int t = threadIdx.x;
    int lp = t & 63;
    int pvalid = (p0 + lp) < P_;
    const float* src = enc + (size_t)b * CP_ + (size_t)c0 * P_ + p0 + lp;
#pragma unroll
    for (int i = 0; i < 16; ++i) {
        int c = i * 4 + (t >> 6);
        float f = pvalid ? src[(size_t)c * P_] : 0.0f;
        tile[lp][c] = f2bf(f);
    }
    __syncthreads();
    // write: each p-row is 128B of bf16; 32 lanes x 4B per row
    int pw = t >> 5;                 // 0..7, 8 passes
    int ci = (t & 31) * 2;
#pragma unroll
    for (int i = 0; i < 8; ++i) {
        int p = pw + i * 8;
        if (p0 + p < P_) {
            *(unsigned int*)&fT[(size_t)(b * P_ + p0 + p) * C_ + c0 + ci] =
                *(const unsigned int*)&tile[p][ci];
        }
    }
}

// ---------------------------------------------------------------------------
// Kernel 1: Wt[a][c] = bf16(W_enc[c][a])   (2048x512 -> 512x2048)
// ---------------------------------------------------------------------------
__global__ __launch_bounds__(256) void k_transpose_wenc(const float* __restrict__ W,
                                                        u16* __restrict__ Wt) {
    __shared__ u16 tile[64][65];
    int t  = threadIdx.x;
    int cb = (blockIdx.x & 31) * 64;   // 32 c-blocks
    int ab = (blockIdx.x >> 5) * 64;   // 8  a-blocks
#pragma unroll
    for (int i = 0; i < 16; ++i) {
        int c = (t >> 6) + i * 4;
        int a = t & 63;
        tile[c][a] = f2bf(W[(size_t)(cb + c) * A_ + ab + a]);
    }
    __syncthreads();
#pragma unroll
    for (int i = 0; i < 16; ++i) {
        int a  = (t >> 6) + i * 4;
        int cl = t & 63;
        Wt[(size_t)(ab + a) * C_ + cb + cl] = tile[cl][a];
    }
}

// ---------------------------------------------------------------------------
// Kernel 2: dec_att[b][a] = dh[b] @ W_dec[:,a] + b_dec[a]
// ---------------------------------------------------------------------------
__global__ __launch_bounds__(512) void k_dec_att(const float* __restrict__ dh,
                                                 const float* __restrict__ Wd,
                                                 const float* __restrict__ bd,
                                                 float* __restrict__ out) {
    __shared__ float hL[512];
    int b = blockIdx.x, t = threadIdx.x;
    hL[t] = dh[b * 512 + t];
    __syncthreads();
    float s = bd[t];
#pragma unroll 8
    for (int k = 0; k < 512; ++k) s = fmaf(hL[k], Wd[k * 512 + t], s);
    out[b * 512 + t] = s;
}

// ---------------------------------------------------------------------------
// Kernel 3: fused att GEMM. Per block: 64 rows x 512 a, K=2048, BK=64.
// A-operand = Wt rows (m=a), B-operand = fT rows (n=r).
// LDS in MFMA-fragment order, staged by global_load_lds dwordx4:
//   group of 16 rows x 32 k = 1KB block: lane l holds (row=l&15, k=(l>>4)*8..+7)
// ---------------------------------------------------------------------------
__global__ __launch_bounds__(512, 2) void k_gemm_att(const u16* __restrict__ fT,
                                                     const u16* __restrict__ Wt,
                                                     const float* __restrict__ dec_att,
                                                     const float* __restrict__ benc,
                                                     const float* __restrict__ wfull,
                                                     const float* __restrict__ bfull,
                                                     float* __restrict__ att) {
    __shared__ u16   As[2 * 4 * 512];    // 8KB  [kstep][rgrp(4)][64 lanes x 8 u16]
    __shared__ u16   Bs[2 * 32 * 512];   // 64KB [kstep][agrp(32)][64 lanes x 8 u16]
    __shared__ float decL[2][512];
    __shared__ float wL[512];
    __shared__ float att_part[512];

    const int t    = threadIdx.x;
    const int lane = t & 63;
    const int wv   = t >> 6;
    const int l16  = lane & 15;
    const int lq   = lane >> 4;
    const int row0 = blockIdx.x * 64;

    const int b0 = row0 / 196;
    const int b1 = (row0 + 63) / 196;
    decL[0][t] = dec_att[b0 * 512 + t] + benc[t];
    decL[1][t] = dec_att[b1 * 512 + t] + benc[t];
    wL[t]      = wfull[t];
    att_part[t] = 0.0f;

    // A staging: one 16B load / thread / iter. wave wv -> (kstep=wv>>2, rgrp=wv&3)
    const u16* srcA = fT + (size_t)(row0 + (wv & 3) * 16 + l16) * C_ + (wv >> 2) * 32 + lq * 8;
    u16* dstA = As + wv * 512 + lane * 8;
    // B staging: 8 x 16B loads / thread / iter. g = wv*8+i -> (kstep=g>>5, agrp=g&31)
    const u16* srcB = Wt + (size_t)l16 * C_ + lq * 8;
    u16* dstB = Bs + (wv * 8) * 512 + lane * 8;

    const int wr = wv & 1;     // 32-row half
    const int wa = wv >> 1;    // 128-a quarter
    f32x4 acc[8][2] = {};

    for (int k0 = 0; k0 < C_; k0 += 64) {
        __syncthreads();
        gl_lds16(srcA + k0, dstA);
#pragma unroll
        for (int i = 0; i < 8; ++i) {
            int g = wv * 8 + i;
            gl_lds16(srcB + k0 + (size_t)(g & 31) * 16 * C_ + (g >> 5) * 32, dstB + i * 512);
        }
        __syncthreads();
#pragma unroll
        for (int ks = 0; ks < 2; ++ks) {
            bf16x8 bfr[2], afr[8];
#pragma unroll
            for (int tr = 0; tr < 2; ++tr)
                bfr[tr] = *(const bf16x8*)&As[ks * 2048 + (wr * 2 + tr) * 512 + lane * 8];
#pragma unroll
            for (int ta = 0; ta < 8; ++ta)
                afr[ta] = *(const bf16x8*)&Bs[ks * 16384 + (wa * 8 + ta) * 512 + lane * 8];
#pragma unroll
            for (int ta = 0; ta < 8; ++ta)
#pragma unroll
                for (int tr = 0; tr < 2; ++tr)
                    acc[ta][tr] = __builtin_amdgcn_mfma_f32_16x16x32_bf16(afr[ta], bfr[tr],
                                                                          acc[ta][tr], 0, 0, 0);
        }
    }

    // epilogue: relu + dot(w_full), reduce over a
    const int col = l16, quad = lq;
#pragma unroll
    for (int tr = 0; tr < 2; ++tr) {
        int rgl = wr * 32 + tr * 16 + col;
        int rgg = row0 + rgl;
        int bi  = rgg / 196 - b0;
        float s = 0.0f;
#pragma unroll
        for (int ta = 0; ta < 8; ++ta)
#pragma unroll
            for (int rr = 0; rr < 4; ++rr) {
                int a_idx = wa * 128 + ta * 16 + quad * 4 + rr;
                float v = acc[ta][tr][rr] + decL[bi][a_idx];
                s = fmaf(fmaxf(v, 0.0f), wL[a_idx], s);
            }
        s += __shfl_xor(s, 16);
        s += __shfl_xor(s, 32);
        if (quad == 0) att_part[wv * 64 + rgl] = s;
    }
    __syncthreads();
    if (t < 64) {
        float s = bfull[0];
#pragma unroll
        for (int w = 0; w < 8; ++w) s += att_part[w * 64 + t];
        att[row0 + t] = s;
    }
}

// ---------------------------------------------------------------------------
// Kernel 4: softmax over 196 pixels per batch (1 wave per batch)
// ---------------------------------------------------------------------------
__global__ __launch_bounds__(64) void k_softmax(const float* __restrict__ att,
                                                float* __restrict__ alpha) {
    int b = blockIdx.x, lane = threadIdx.x;
    const float* a = att + b * P_;
    float v[4];
    float mx = -__builtin_inff();
#pragma unroll
    for (int i = 0; i < 4; ++i) {
        int p = lane + i * 64;
        v[i] = (p < P_) ? a[p] : -__builtin_inff();
        mx = fmaxf(mx, v[i]);
    }
#pragma unroll
    for (int off = 32; off >= 1; off >>= 1) mx = fmaxf(mx, __shfl_xor(mx, off));
    float sum = 0.0f;
#pragma unroll
    for (int i = 0; i < 4; ++i) {
        int p = lane + i * 64;
        float e = (p < P_) ? expf(v[i] - mx) : 0.0f;
        v[i] = e;
        sum += e;
    }
#pragma unroll
    for (int off = 32; off >= 1; off >>= 1) sum += __shfl_xor(sum, off);
    float inv = 1.0f / sum;
#pragma unroll
    for (int i = 0; i < 4; ++i) {
        int p = lane + i * 64;
        if (p < P_) alpha[b * P_ + p] = v[i] * inv;
    }
}

// ---------------------------------------------------------------------------
// Kernel 5: context[b][c] = sum_p fT[b*196+p][c] * alpha[b][p]
// block = (b, c-half of 1024); thread owns 4 c; 8B bf16x4 loads, coalesced.
// ---------------------------------------------------------------------------
__global__ __launch_bounds__(256) void k_context(const u16* __restrict__ fT,
                                                 const float* __restrict__ alpha,
                                                 float* __restrict__ ctx) {
    __shared__ float aL[200];
    int b = blockIdx.x >> 1;
    int half = blockIdx.x & 1;
    int t = threadIdx.x;
    if (t < P_) aL[t] = alpha[b * P_ + t];
    __syncthreads();
    int c0 = half * 1024 + t * 4;
    const u16* base = fT + (size_t)b * P_ * C_ + c0;
    float s0 = 0.f, s1 = 0.f, s2 = 0.f, s3 = 0.f;
#pragma unroll 4
    for (int p = 0; p < P_; ++p) {
        bf16x4 v = *(const bf16x4*)(base + (size_t)p * C_);
        float a = aL[p];
        s0 = fmaf((float)v[0], a, s0);
        s1 = fmaf((float)v[1], a, s1);
        s2 = fmaf((float)v[2], a, s2);
        s3 = fmaf((float)v[3], a, s3);
    }
    float4 o = {s0, s1, s2, s3};
    *(float4*)&ctx[(size_t)b * C_ + c0] = o;
}

// ---------------------------------------------------------------------------
extern "C" void kernel_launch(void* const* d_in, const int* in_sizes, int n_in,
                              void* d_out, int out_size, void* d_ws, size_t ws_size,
                              hipStream_t stream) {
    const float* enc   = (const float*)d_in[0];
    const float* dh    = (const float*)d_in[1];
    const float* Wenc  = (const float*)d_in[2];
    const float* benc  = (const float*)d_in[3];
    const float* Wdec  = (const float*)d_in[4];
    const float* bdec  = (const float*)d_in[5];
    const float* wfull = (const float*)d_in[6];
    const float* bfull = (const float*)d_in[7];

    // workspace layout
    const size_t fT_bytes = (size_t)MTOT * C_ * sizeof(u16);   // 205,520,896
    u16*   fT  = (u16*)d_ws;
    char*  rest = (char*)d_ws + fT_bytes;
    u16*   Wt  = (u16*)rest;                                   // 2 MB
    float* dec = (float*)(rest + (2u << 20));                  // 512 KB
    float* att = (float*)(rest + (2u << 20) + (512u << 10));   // 200 KB

    float* ctx     = (float*)d_out;          // [256][2048]
    float* alpha_o = ctx + B_ * C_;          // [256][196]

    k_prep_feats<<<dim3(B_ * 32 * 4), dim3(256), 0, stream>>>(enc, fT);
    k_transpose_wenc<<<dim3(256), dim3(256), 0, stream>>>(Wenc, Wt);
    k_dec_att<<<dim3(256), dim3(512), 0, stream>>>(dh, Wdec, bdec, dec);
    k_gemm_att<<<dim3(MTOT / 64), dim3(512), 0, stream>>>(fT, Wt, dec, benc,
                                                          wfull, bfull, att);
    k_softmax<<<dim3(256), dim3(64), 0, stream>>>(att, alpha_o);
    k_context<<<dim3(512), dim3(256), 0, stream>>>(fT, alpha_o, ctx);
}

// Round 3
// 820.101 us; speedup vs baseline: 1.4056x; 1.2303x over previous
//
#include <hip/hip_runtime.h>

typedef unsigned short u16;
typedef __bf16 bf16x8 __attribute__((ext_vector_type(8)));
typedef float f32x4 __attribute__((ext_vector_type(4)));

#define B_   256
#define C_   2048
#define P_   196
#define A_   512
#define CP_  (C_ * P_)        // 401408
#define MTOT (B_ * P_)        // 50176 = 392 * 128

#define BM 128                // rows per block
#define BK 32                 // k per iter (one 16x16x32 kstep)

__device__ __forceinline__ u16 f2bf(float f) {
    unsigned int x = __float_as_uint(f);
    unsigned int r = (x + 0x7fffu + ((x >> 16) & 1u)) >> 16;   // RNE
    return (u16)r;
}

// async global->LDS 16B copy; LDS dest must be wave-uniform base + lane*16
__device__ __forceinline__ void gl_lds16(const void* g, void* l) {
    __builtin_amdgcn_global_load_lds(
        (const __attribute__((address_space(1))) unsigned int*)g,
        (__attribute__((address_space(3))) unsigned int*)l, 16, 0, 0);
}

// ---------------------------------------------------------------------------
// Kernel 1: Wt[a][c] = bf16(W_enc[c][a])   (2048x512 -> 512x2048)
// ---------------------------------------------------------------------------
__global__ __launch_bounds__(256) void k_transpose_wenc(const float* __restrict__ W,
                                                        u16* __restrict__ Wt) {
    __shared__ u16 tile[64][65];
    int t  = threadIdx.x;
    int cb = (blockIdx.x & 31) * 64;
    int ab = (blockIdx.x >> 5) * 64;
#pragma unroll
    for (int i = 0; i < 16; ++i) {
        int c = (t >> 6) + i * 4;
        int a = t & 63;
        tile[c][a] = f2bf(W[(size_t)(cb + c) * A_ + ab + a]);
    }
    __syncthreads();
#pragma unroll
    for (int i = 0; i < 16; ++i) {
        int a  = (t >> 6) + i * 4;
        int cl = t & 63;
        Wt[(size_t)(ab + a) * C_ + cb + cl] = tile[cl][a];
    }
}

// ---------------------------------------------------------------------------
// Kernel 2: dec_att[b][a] = dh[b] @ W_dec[:,a] + b_dec[a]
// ---------------------------------------------------------------------------
__global__ __launch_bounds__(512) void k_dec_att(const float* __restrict__ dh,
                                                 const float* __restrict__ Wd,
                                                 const float* __restrict__ bd,
                                                 float* __restrict__ out) {
    __shared__ float hL[512];
    int b = blockIdx.x, t = threadIdx.x;
    hL[t] = dh[b * 512 + t];
    __syncthreads();
    float s = bd[t];
#pragma unroll 8
    for (int k = 0; k < 512; ++k) s = fmaf(hL[k], Wd[k * 512 + t], s);
    out[b * 512 + t] = s;
}

// ---------------------------------------------------------------------------
// Kernel 3: fused att GEMM. Block: 128 rows x 512 a, K=2048, BK=32.
// 1024 threads = 16 waves, wave tile 64r x 64a (acc 4x4 of 16x16).
// A-operand = Wt rows (m=a), via global_load_lds dwordx4 (fragment order).
// B-operand = feats rows: read enc fp32 coalesced, cvt bf16 in-reg,
//             ds_write_b64 into fragment order.  Single barrier per iter,
//             double-buffered As/Bs: next-iter loads fly during MFMA.
// ---------------------------------------------------------------------------
__global__ __launch_bounds__(1024, 4) void k_gemm_att(const float* __restrict__ enc,
                                                      const u16* __restrict__ Wt,
                                                      const float* __restrict__ dec_att,
                                                      const float* __restrict__ benc,
                                                      const float* __restrict__ wfull,
                                                      const float* __restrict__ bfull,
                                                      float* __restrict__ att) {
    __shared__ u16   As[2][8 * 512];     // 8KB/buf : feats frags, 8 rgrps
    __shared__ u16   Bs[2][32 * 512];    // 32KB/buf: Wt frags, 32 agrps
    __shared__ float decL[2][512];
    __shared__ float wL[512];
    __shared__ float att_part[8][128];

    const int t    = threadIdx.x;
    const int lane = t & 63;
    const int wv   = t >> 6;             // 0..15
    const int l16  = lane & 15;
    const int lq   = lane >> 4;
    const int row0 = blockIdx.x * BM;

    const int b0 = row0 / 196;
    const int b1 = (row0 + BM - 1) / 196;
    if (t < 512) {
        decL[0][t] = dec_att[b0 * 512 + t] + benc[t];
        wL[t] = wfull[t];
    } else {
        decL[1][t - 512] = dec_att[b1 * 512 + (t - 512)] + benc[t - 512];
    }

    // ---- A (feats) staging map: thread = (pl, kq); 4 elems, k = kq*4+j ----
    const int kq = t & 7;                // 8 k-quads of 4
    const int pl = t >> 3;               // 0..127 local row
    const int pg = row0 + pl;
    const int bb = pg / 196;
    const int pp = pg - bb * 196;
    const float* srcA = enc + (size_t)bb * CP_ + (size_t)(kq * 4) * P_ + pp;
    // frag slot: lane = (pl&15) + 16*(kq>>1), u16 sub-off (kq&1)*4
    const int a_off = (pl >> 4) * 512 + ((pl & 15) + 16 * (kq >> 1)) * 8 + (kq & 1) * 4;

    // ---- B (Wt) staging: 2 x global_load_lds dwordx4 per thread ----------
    const u16* srcB = Wt + (size_t)(wv * 2 * 16 + l16) * C_ + lq * 8;
    const int  b_off = (wv * 2) * 512 + lane * 8;

    // ---- wave tile --------------------------------------------------------
    const int wr = wv & 1;               // 64-row half
    const int wa = wv >> 1;              // 0..7 : 64-a slice

    f32x4 acc[4][4] = {};                // [ta][tr]

    // ---- prologue: buffer 0 ----------------------------------------------
    float av[4];
#pragma unroll
    for (int j = 0; j < 4; ++j) av[j] = srcA[(size_t)j * P_];
    {
        unsigned int lo = (unsigned int)f2bf(av[0]) | ((unsigned int)f2bf(av[1]) << 16);
        unsigned int hi = (unsigned int)f2bf(av[2]) | ((unsigned int)f2bf(av[3]) << 16);
        *(unsigned long long*)&As[0][a_off] =
            (unsigned long long)lo | ((unsigned long long)hi << 32);
    }
    gl_lds16(srcB, &Bs[0][b_off]);
    gl_lds16(srcB + (size_t)16 * C_, &Bs[0][b_off + 512]);

    int p = 0;
    for (int k = 0; k < C_ / BK; ++k) {
        __syncthreads();                 // As[p], Bs[p] ready (DMA drained)
        if (k + 1 < C_ / BK) {
            const u16* sB = srcB + (k + 1) * BK;
            gl_lds16(sB, &Bs[p ^ 1][b_off]);
            gl_lds16(sB + (size_t)16 * C_, &Bs[p ^ 1][b_off + 512]);
            const float* sA = srcA + (size_t)(k + 1) * BK * P_;
#pragma unroll
            for (int j = 0; j < 4; ++j) av[j] = sA[(size_t)j * P_];
        }
        // fragments + MFMA from buffer p
        bf16x8 bfr[4];
#pragma unroll
        for (int tr = 0; tr < 4; ++tr)
            bfr[tr] = *(const bf16x8*)&As[p][(wr * 4 + tr) * 512 + lane * 8];
#pragma unroll
        for (int ta = 0; ta < 4; ++ta) {
            bf16x8 afr = *(const bf16x8*)&Bs[p][(wa * 4 + ta) * 512 + lane * 8];
#pragma unroll
            for (int tr = 0; tr < 4; ++tr)
                acc[ta][tr] = __builtin_amdgcn_mfma_f32_16x16x32_bf16(afr, bfr[tr],
                                                                      acc[ta][tr], 0, 0, 0);
        }
        if (k + 1 < C_ / BK) {
            unsigned int lo = (unsigned int)f2bf(av[0]) | ((unsigned int)f2bf(av[1]) << 16);
            unsigned int hi = (unsigned int)f2bf(av[2]) | ((unsigned int)f2bf(av[3]) << 16);
            *(unsigned long long*)&As[p ^ 1][a_off] =
                (unsigned long long)lo | ((unsigned long long)hi << 32);
        }
        p ^= 1;
    }

    // ---- epilogue: relu + dot(w_full), reduce over a ---------------------
    const int col = l16, quad = lq;
#pragma unroll
    for (int tr = 0; tr < 4; ++tr) {
        int rgl = wr * 64 + tr * 16 + col;
        int rgg = row0 + rgl;
        int bi  = rgg / 196 - b0;
        float s = 0.0f;
#pragma unroll
        for (int ta = 0; ta < 4; ++ta)
#pragma unroll
            for (int rr = 0; rr < 4; ++rr) {
                int a_idx = wa * 64 + ta * 16 + quad * 4 + rr;
                float v = acc[ta][tr][rr] + decL[bi][a_idx];
                s = fmaf(fmaxf(v, 0.0f), wL[a_idx], s);
            }
        s += __shfl_xor(s, 16);
        s += __shfl_xor(s, 32);
        if (quad == 0) att_part[wa][rgl] = s;
    }
    __syncthreads();
    if (t < BM) {
        float s = bfull[0];
#pragma unroll
        for (int w = 0; w < 8; ++w) s += att_part[w][t];
        att[row0 + t] = s;
    }
}

// ---------------------------------------------------------------------------
// Kernel 4: softmax over 196 pixels per batch (1 wave per batch)
// ---------------------------------------------------------------------------
__global__ __launch_bounds__(64) void k_softmax(const float* __restrict__ att,
                                                float* __restrict__ alpha) {
    int b = blockIdx.x, lane = threadIdx.x;
    const float* a = att + b * P_;
    float v[4];
    float mx = -__builtin_inff();
#pragma unroll
    for (int i = 0; i < 4; ++i) {
        int p = lane + i * 64;
        v[i] = (p < P_) ? a[p] : -__builtin_inff();
        mx = fmaxf(mx, v[i]);
    }
#pragma unroll
    for (int off = 32; off >= 1; off >>= 1) mx = fmaxf(mx, __shfl_xor(mx, off));
    float sum = 0.0f;
#pragma unroll
    for (int i = 0; i < 4; ++i) {
        int p = lane + i * 64;
        float e = (p < P_) ? expf(v[i] - mx) : 0.0f;
        v[i] = e;
        sum += e;
    }
#pragma unroll
    for (int off = 32; off >= 1; off >>= 1) sum += __shfl_xor(sum, off);
    float inv = 1.0f / sum;
#pragma unroll
    for (int i = 0; i < 4; ++i) {
        int p = lane + i * 64;
        if (p < P_) alpha[b * P_ + p] = v[i] * inv;
    }
}

// ---------------------------------------------------------------------------
// Kernel 5: context[b][c] = sum_p enc[b][c][p] * alpha[b][p]   (fp32 exact)
// block = (b, chunk of 64 c); wave handles 16 c rows; float4 over p (196=49*4)
// ---------------------------------------------------------------------------
__global__ __launch_bounds__(256) void k_context(const float* __restrict__ enc,
                                                 const float* __restrict__ alpha,
                                                 float* __restrict__ ctx) {
    __shared__ float aL[256];
    int t = threadIdx.x;
    int b = blockIdx.x >> 5;
    int chunk = blockIdx.x & 31;
    aL[t] = (t < P_) ? alpha[b * P_ + t] : 0.0f;
    __syncthreads();
    int wv = t >> 6, lane = t & 63;
    int cbase = chunk * 64 + wv * 16;
    const float* base = enc + (size_t)b * CP_;
#pragma unroll 4
    for (int i = 0; i < 16; ++i) {
        int c = cbase + i;
        float s = 0.0f;
        if (lane < 49) {
            float4 f = *(const float4*)(base + (size_t)c * P_ + lane * 4);
            float4 a4 = *(const float4*)&aL[lane * 4];
            s = f.x * a4.x + f.y * a4.y + f.z * a4.z + f.w * a4.w;
        }
#pragma unroll
        for (int off = 32; off >= 1; off >>= 1) s += __shfl_xor(s, off);
        if (lane == 0) ctx[(size_t)b * C_ + c] = s;
    }
}

// ---------------------------------------------------------------------------
extern "C" void kernel_launch(void* const* d_in, const int* in_sizes, int n_in,
                              void* d_out, int out_size, void* d_ws, size_t ws_size,
                              hipStream_t stream) {
    const float* enc   = (const float*)d_in[0];
    const float* dh    = (const float*)d_in[1];
    const float* Wenc  = (const float*)d_in[2];
    const float* benc  = (const float*)d_in[3];
    const float* Wdec  = (const float*)d_in[4];
    const float* bdec  = (const float*)d_in[5];
    const float* wfull = (const float*)d_in[6];
    const float* bfull = (const float*)d_in[7];

    u16*   Wt  = (u16*)d_ws;                                        // 2 MB
    float* dec = (float*)((char*)d_ws + (2u << 20));                // 512 KB
    float* att = (float*)((char*)d_ws + (2u << 20) + (512u << 10)); // 200 KB

    float* ctx     = (float*)d_out;          // [256][2048]
    float* alpha_o = ctx + B_ * C_;          // [256][196]

    k_transpose_wenc<<<dim3(256), dim3(256), 0, stream>>>(Wenc, Wt);
    k_dec_att<<<dim3(256), dim3(512), 0, stream>>>(dh, Wdec, bdec, dec);
    k_gemm_att<<<dim3(MTOT / BM), dim3(1024), 0, stream>>>(enc, Wt, dec, benc,
                                                           wfull, bfull, att);
    k_softmax<<<dim3(256), dim3(64), 0, stream>>>(att, alpha_o);
    k_context<<<dim3(256 * 32), dim3(256), 0, stream>>>(enc, alpha_o, ctx);
}